// Round 7
// baseline (328.877 us; speedup 1.0000x reference)
//
#include <hip/hip_runtime.h>
#include <stdint.h>

#define NNODES 10000
#define NEDGES 100000
#define DNODE 56
#define JTOT 1600
#define HBLK 391   // hidden-GEMM blocks
#define TBLK 400   // G-transpose blocks

typedef __attribute__((ext_vector_type(8))) short short8;
typedef __attribute__((ext_vector_type(4))) float floatx4;

__device__ __forceinline__ unsigned short f2bf(float f) {
  unsigned u = __float_as_uint(f);
  u = u + 0x7fffu + ((u >> 16) & 1u);
  return (unsigned short)(u >> 16);
}
__device__ __forceinline__ float bf2f(unsigned short u) {
  return __uint_as_float(((unsigned)u) << 16);
}

__device__ __forceinline__ float mishf(float x) {
  float e = __expf(x);
  float z = 1.f + e; z = z * z;
  float t = (z - 1.f) / (z + 1.f);
  t = (x > 40.f) ? 1.f : t;
  return x * t;
}

// async 16B global -> LDS (DMA, no VGPR round trip). lds must be wave-uniform base.
__device__ __forceinline__ void async_ld16(void* lds, const void* gp) {
  __builtin_amdgcn_global_load_lds(
      (const __attribute__((address_space(1))) unsigned int*)gp,
      (__attribute__((address_space(3))) unsigned int*)lds, 16, 0, 0);
}

// ---- fused: blocks [0,HBLK) h = mish(ea@fc1+b1) + src histogram;
//             [HBLK,HBLK+TBLK) G = bf16(fc2w^T) PRE-SWIZZLED for k_tp's LDS frag reads;
//             last block to finish: 256-thread scan -> offs/cursor.
__global__ __launch_bounds__(256) void k_hidtr(const float* __restrict__ ea,
                                               const float* __restrict__ fc1w,
                                               const float* __restrict__ fc1b,
                                               const float* __restrict__ fc2w,
                                               const int* __restrict__ eidx,
                                               int* __restrict__ cntn,
                                               int* __restrict__ done,
                                               int* __restrict__ offs,
                                               int* __restrict__ cursor,
                                               unsigned short* __restrict__ hb,
                                               unsigned short* __restrict__ G) {
  __shared__ int ssum[256];
  __shared__ int amLast;
  const int bid = blockIdx.x, t = threadIdx.x;
  if (bid >= HBLK) {
    int idx = (bid - HBLK) * 256 + t;
    if (idx < 64 * JTOT) {
      // destination idx -> (jt, col, slot, s); inverse swizzle g = slot ^ (col&7)
      int jt = idx >> 10, r = idx & 1023;
      int col = r >> 6, w = r & 63;
      int slot = w >> 3, s = w & 7;
      int g = slot ^ (col & 7);
      int k = g * 8 + s;
      int j = jt * 16 + col;
      G[idx] = f2bf(fc2w[k * JTOT + j]);
    }
  } else {
    int e = bid * 256 + t;
    if (e < NEDGES) {
      atomicAdd(&cntn[eidx[e]], 1);
      float a[64];
      const float4* row = (const float4*)(ea + (size_t)e * 64);
      #pragma unroll
      for (int i = 0; i < 16; i++) {
        float4 v = row[i];
        a[4*i] = v.x; a[4*i+1] = v.y; a[4*i+2] = v.z; a[4*i+3] = v.w;
      }
      for (int jb = 0; jb < 64; jb += 8) {
        float acc[8];
        #pragma unroll
        for (int i = 0; i < 8; i++) acc[i] = fc1b[jb + i];
        #pragma unroll
        for (int k = 0; k < 64; k++) {
          #pragma unroll
          for (int i = 0; i < 8; i++) acc[i] = fmaf(a[k], fc1w[k*64 + jb + i], acc[i]);
        }
        unsigned pk[4];
        #pragma unroll
        for (int i = 0; i < 4; i++) {
          unsigned lo = f2bf(mishf(acc[2*i]));
          unsigned hi = f2bf(mishf(acc[2*i+1]));
          pk[i] = lo | (hi << 16);
        }
        *(uint4*)(hb + (size_t)e*64 + jb) = make_uint4(pk[0], pk[1], pk[2], pk[3]);
      }
    }
  }
  // ---- last-block scan (threadfence + counter pattern)
  __syncthreads();
  if (t == 0) {
    __threadfence();
    amLast = (atomicAdd(done, 1) == (HBLK + TBLK) - 1) ? 1 : 0;
  }
  __syncthreads();
  if (amLast) {
    __threadfence();
    int c[40]; int s = 0;
    #pragma unroll 4
    for (int i = 0; i < 40; i++) {
      int idx = t*40 + i;
      int v = (idx < NNODES) ? atomicAdd(&cntn[idx], 0) : 0;
      c[i] = v; s += v;
    }
    ssum[t] = s;
    __syncthreads();
    for (int o = 1; o < 256; o <<= 1) {
      int v = (t >= o) ? ssum[t - o] : 0;
      __syncthreads();
      ssum[t] += v;
      __syncthreads();
    }
    int run = (t == 0) ? 0 : ssum[t - 1];
    for (int i = 0; i < 40; i++) {
      int idx = t*40 + i;
      if (idx < NNODES) { offs[idx] = run; cursor[idx] = run; run += c[i]; }
    }
    if (t == 255) offs[NNODES] = ssum[255];
  }
}

// ---- fused GEMM2 + tensor product. 256 thr = 4 waves x 32 edges.
// G staged in LDS, double-buffered 10-tile chunks (20KB) via global_load_lds,
// chunk order staggered by blockIdx%10 (j-accumulation commutes) to spread L2.
// Coef tables bf16 per-wave LDS (R5-verified precision). 11 barriers total.
__global__ __launch_bounds__(256, 2) void k_tp(
    const unsigned short* __restrict__ hb,
    const unsigned short* __restrict__ G,     // pre-swizzled
    const float* __restrict__ fc2b,
    const int* __restrict__ eidx,
    const float* __restrict__ node_attr,
    const float* __restrict__ edge_sh,
    int* __restrict__ cursor,
    float* __restrict__ tp) {
  __shared__ short Gs[2][10 * 1024];          // 40,960 B
  __shared__ unsigned short wls[4][64 * 32];  // 16,384 B bf16 coef tables
  __shared__ float b2s[JTOT];                 //  6,400 B
  __shared__ int pos_s[4][32];                //    512 B   (total 64,256 B)
  const int tid = threadIdx.x;
  const int wave = tid >> 6, lane = tid & 63;
  for (int i = tid; i < JTOT; i += 256) b2s[i] = fc2b[i];

  const int e0w = blockIdx.x * 128 + wave * 32;
  unsigned short* Wt = &wls[wave][0];
  {
    int el = lane & 31, hh = lane >> 5;
    int e = e0w + el;
    bool valid = e < NEDGES;
    int dst = valid ? eidx[NEDGES + e] : 0;
    const float* na = node_attr + (size_t)dst * DNODE;
    if (hh == 0) {
      pos_s[wave][el] = valid ? atomicAdd(&cursor[eidx[e]], 1) : 0;
      #pragma unroll
      for (int u = 0; u < 32; u += 4) {
        float4 v = valid ? *(const float4*)(na + u) : make_float4(0.f,0.f,0.f,0.f);
        Wt[(u+0)*32 + el] = f2bf(v.x);
        Wt[(u+1)*32 + el] = f2bf(v.y);
        Wt[(u+2)*32 + el] = f2bf(v.z);
        Wt[(u+3)*32 + el] = f2bf(v.w);
      }
    } else {
      float4 sh = valid ? *(const float4*)(edge_sh + 4*(size_t)e) : make_float4(0.f,0.f,0.f,0.f);
      const float rs3 = 0.57735026918962576f;
      #pragma unroll
      for (int u = 0; u < 8; u++) {
        float v0 = valid ? na[32 + u*3 + 0] : 0.f;
        float v1 = valid ? na[32 + u*3 + 1] : 0.f;
        float v2 = valid ? na[32 + u*3 + 2] : 0.f;
        Wt[(32 + u*3 + 0)*32 + el] = f2bf(v0);
        Wt[(32 + u*3 + 1)*32 + el] = f2bf(v1);
        Wt[(32 + u*3 + 2)*32 + el] = f2bf(v2);
        Wt[(56 + u)*32 + el] = f2bf((v0*sh.y + v1*sh.z + v2*sh.w) * rs3);
      }
    }
  }

  const int col = lane & 15, rg = lane >> 4, rgh = rg >> 1;
  const int g0 = (rg ^ (col & 7)) * 8;        // swizzled frag granule offsets
  const int g1 = ((rg + 4) ^ (col & 7)) * 8;
  float sh0c[2], sh1c[2][3];
  bool vld[2];
  short8 bfrag[2][2];
  const short8 zfrag = {0,0,0,0,0,0,0,0};
  #pragma unroll
  for (int nt = 0; nt < 2; nt++) {
    int e = e0w + nt*16 + col;
    bool v = e < NEDGES; vld[nt] = v;
    if (v) {
      float4 sh = *(const float4*)(edge_sh + 4*(size_t)e);
      sh0c[nt] = sh.x; sh1c[nt][0] = sh.y; sh1c[nt][1] = sh.z; sh1c[nt][2] = sh.w;
      const unsigned short* hp = hb + (size_t)e * 64;
      bfrag[nt][0] = *(const short8*)(hp + rg*8);
      bfrag[nt][1] = *(const short8*)(hp + 32 + rg*8);
    } else {
      sh0c[nt] = 0.f; sh1c[nt][0] = sh1c[nt][1] = sh1c[nt][2] = 0.f;
      bfrag[nt][0] = zfrag; bfrag[nt][1] = zfrag;
    }
  }

  float sacc[2][8], vacc[2][12];
  #pragma unroll
  for (int nt = 0; nt < 2; nt++) {
    #pragma unroll
    for (int i = 0; i < 8; i++) sacc[nt][i] = 0.f;
    #pragma unroll
    for (int i = 0; i < 12; i++) vacc[nt][i] = 0.f;
  }

  // stage chunk ch (10 tiles, 20,480 B = 1280 x 16B granules) into Gs[b]
  auto stage = [&](int ch, int b) {
    const unsigned short* gsrc = G + (size_t)ch * 10240 + tid * 8;
    #pragma unroll
    for (int i = 0; i < 5; i++)
      async_ld16(&Gs[b][(i*256 + wave*64) * 8], gsrc + i*256*8);
  };

  const int cc0 = blockIdx.x % 10;
  stage(cc0, 0);
  __syncthreads();

  int buf = 0;
  #pragma unroll 1
  for (int cc = 0; cc < 10; cc++) {
    int c = cc0 + cc; if (c >= 10) c -= 10;
    if (cc < 9) { int cn = c + 1; if (cn >= 10) cn = 0; stage(cn, buf ^ 1); }
    #pragma unroll 1
    for (int t = 0; t < 10; t++) {
      const int jt = c * 10 + t;
      const short* gb = &Gs[buf][t * 1024];
      short8 x0 = *(const short8*)(gb + col*64 + g0);
      short8 x1 = *(const short8*)(gb + col*64 + g1);
      float4 bb = *(const float4*)&b2s[jt*16 + rg*4];
      floatx4 acc[2];
      #pragma unroll
      for (int nt = 0; nt < 2; nt++) {
        floatx4 a = {bb.x, bb.y, bb.z, bb.w};
        a = __builtin_amdgcn_mfma_f32_16x16x32_bf16(x0, bfrag[nt][0], a, 0, 0, 0);
        a = __builtin_amdgcn_mfma_f32_16x16x32_bf16(x1, bfrag[nt][1], a, 0, 0, 0);
        acc[nt] = a;
      }
      if (jt < 64) {                   // w1: u = jt>>1, slot p = jt&1
        const int u = jt >> 1, p = jt & 1;
        #pragma unroll
        for (int nt = 0; nt < 2; nt++) {
          float cf = bf2f(Wt[u*32 + nt*16 + col]) * sh0c[nt];
          #pragma unroll
          for (int r = 0; r < 4; r++)
            sacc[nt][p*4+r] = fmaf(cf, acc[nt][r], sacc[nt][p*4+r]);
        }
      } else if (jt < 68) {            // w2: u = (jt-64)*2+rgh
        const int u = (jt - 64)*2 + rgh;
        #pragma unroll
        for (int nt = 0; nt < 2; nt++) {
          #pragma unroll
          for (int q = 0; q < 3; q++) {
            float cf = bf2f(Wt[(32 + u*3 + q)*32 + nt*16 + col]) * sh0c[nt];
            #pragma unroll
            for (int r = 0; r < 4; r++)
              vacc[nt][q*4+r] = fmaf(cf, acc[nt][r], vacc[nt][q*4+r]);
          }
        }
      } else if (jt < 84) {            // w3: u = (jt-68)*2+rgh
        const int u = (jt - 68)*2 + rgh;
        #pragma unroll
        for (int nt = 0; nt < 2; nt++) {
          float sv = bf2f(Wt[u*32 + nt*16 + col]);
          #pragma unroll
          for (int q = 0; q < 3; q++) {
            float cf = sv * sh1c[nt][q];
            #pragma unroll
            for (int r = 0; r < 4; r++)
              vacc[nt][q*4+r] = fmaf(cf, acc[nt][r], vacc[nt][q*4+r]);
          }
        }
      } else {                         // w4: u = (jt-84)>>1, slot p = jt&1
        const int u = (jt - 84) >> 1, p = jt & 1;
        #pragma unroll
        for (int nt = 0; nt < 2; nt++) {
          float cf = bf2f(Wt[(56 + u)*32 + nt*16 + col]);
          #pragma unroll
          for (int r = 0; r < 4; r++)
            sacc[nt][p*4+r] = fmaf(cf, acc[nt][r], sacc[nt][p*4+r]);
        }
      }
    }
    buf ^= 1;
    __syncthreads();
  }

  // ---- epilogue: direct stores
  const float ascale = 0.15811388300841897f;   // 1/sqrt(40)
  #pragma unroll
  for (int nt = 0; nt < 2; nt++) {
    int el = nt*16 + col;
    float* rowp = tp + (size_t)pos_s[wave][el] * DNODE;
    if (vld[nt]) {
      #pragma unroll
      for (int p = 0; p < 2; p++) {
        float4 v = make_float4(ascale*sacc[nt][p*4+0], ascale*sacc[nt][p*4+1],
                               ascale*sacc[nt][p*4+2], ascale*sacc[nt][p*4+3]);
        *(float4*)(rowp + p*16 + rg*4) = v;
      }
    }
    float vtot[12];
    #pragma unroll
    for (int k = 0; k < 12; k++)
      vtot[k] = (vacc[nt][k] + __shfl_xor(vacc[nt][k], 32)) * ascale;
    if (rg < 2 && vld[nt]) {
      float tmp[12];
      #pragma unroll
      for (int q = 0; q < 3; q++)
        #pragma unroll
        for (int r = 0; r < 4; r++) tmp[r*3 + q] = vtot[q*4 + r];
      #pragma unroll
      for (int j = 0; j < 3; j++)
        *(float4*)(rowp + 32 + (rg & 1)*12 + j*4) = *(float4*)&tmp[j*4];
    }
  }
}

// ---- per-node mean + residual + BN partials; last block reduces pstat -> stats
__global__ __launch_bounds__(256) void k_gather(const float* __restrict__ tp,
                                                const int* __restrict__ offs,
                                                const float* __restrict__ node_attr,
                                                float* __restrict__ pre,
                                                float* __restrict__ pstat,
                                                int* __restrict__ gdone,
                                                float* __restrict__ stats) {
  __shared__ float redS[4*64], redQ[4*64];
  __shared__ int amLast;
  int t = threadIdx.x, wave = t >> 6, lane = t & 63;
  int gw = blockIdx.x * 4 + wave;
  const int W = 640 * 4;
  int off = (lane < DNODE) ? lane : 0;
  float ssum = 0.f, ssq = 0.f;
  for (int n = gw; n < NNODES; n += W) {
    int beg = offs[n], end = offs[n+1];
    float acc = 0.f;
    int i = beg;
    for (; i + 4 <= end; i += 4) {
      float v0 = tp[(size_t)(i+0)*DNODE + off];
      float v1 = tp[(size_t)(i+1)*DNODE + off];
      float v2 = tp[(size_t)(i+2)*DNODE + off];
      float v3 = tp[(size_t)(i+3)*DNODE + off];
      acc += (v0 + v1) + (v2 + v3);
    }
    for (; i < end; i++) acc += tp[(size_t)i*DNODE + off];
    int c = end - beg; if (c < 1) c = 1;
    float m = acc / (float)c + node_attr[(size_t)n*DNODE + off];
    if (lane < DNODE) { pre[(size_t)n*DNODE + lane] = m; ssum += m; ssq += m*m; }
  }
  redS[wave*64 + lane] = ssum;
  redQ[wave*64 + lane] = ssq;
  __syncthreads();
  if (wave == 0 && lane < DNODE) {
    float a = redS[lane] + redS[64+lane] + redS[128+lane] + redS[192+lane];
    float b = redQ[lane] + redQ[64+lane] + redQ[128+lane] + redQ[192+lane];
    pstat[(size_t)blockIdx.x*112 + lane] = a;
    pstat[(size_t)blockIdx.x*112 + 56 + lane] = b;
  }
  // ---- last-block stats reduction
  __syncthreads();
  if (t == 0) {
    __threadfence();
    amLast = (atomicAdd(gdone, 1) == 639) ? 1 : 0;
  }
  __syncthreads();
  if (amLast) {
    __threadfence();
    int f = t & 127, h = t >> 7;
    float v = 0.f;
    if (f < 112) {
      #pragma unroll 8
      for (int b = h; b < 640; b += 2) v += pstat[(size_t)b*112 + f];
      redS[h*128 + f] = v;
    }
    __syncthreads();
    if (t < 112) stats[t] = redS[t] + redS[128 + t];
  }
}

__global__ __launch_bounds__(256) void k_norm(const float* __restrict__ pre,
                                              const float* __restrict__ stats,
                                              const float* __restrict__ gs,
                                              const float* __restrict__ bs,
                                              const float* __restrict__ gv,
                                              float* __restrict__ out) {
  int idx = blockIdx.x * 256 + threadIdx.x;
  if (idx >= NNODES * DNODE) return;
  int n = idx / DNODE;
  int d = idx - n * DNODE;
  float val = pre[idx];
  const float invN = 1.f / (float)NNODES;
  float res;
  if (d < 32) {
    float mu = stats[d] * invN;
    float var = stats[56 + d] * invN - mu * mu;
    res = (val - mu) * rsqrtf(var + 1e-4f) * gs[d] + bs[d];
  } else {
    int wi = (d - 32) / 3;
    float vn = (stats[56 + 32 + wi*3] + stats[56 + 32 + wi*3 + 1] +
                stats[56 + 32 + wi*3 + 2]) * (invN / 3.f);
    res = val * rsqrtf(vn + 1e-4f) * gv[wi];
  }
  out[idx] = res;
}

extern "C" void kernel_launch(void* const* d_in, const int* in_sizes, int n_in,
                              void* d_out, int out_size, void* d_ws, size_t ws_size,
                              hipStream_t stream) {
  const float* node_attr = (const float*)d_in[0];
  const int*   eidx      = (const int*)d_in[1];
  const float* edge_attr = (const float*)d_in[2];
  const float* edge_sh   = (const float*)d_in[3];
  const float* fc1w      = (const float*)d_in[4];
  const float* fc1b      = (const float*)d_in[5];
  const float* fc2w      = (const float*)d_in[6];
  const float* fc2b      = (const float*)d_in[7];
  const float* gs        = (const float*)d_in[8];
  const float* bs        = (const float*)d_in[9];
  const float* gv        = (const float*)d_in[10];

  float* ws = (float*)d_ws;
  float* tp    = ws;                                    // 5,600,000
  float* pre   = ws + 5600000;                          // 560,000
  float* stats = ws + 6160000;                          // 112 (pad 128)
  float* pstat = ws + 6160128;                          // 640*112 = 71,680
  int*   cntn  = (int*)(ws + 6231808);                  // 10,000
  int*   done  = (int*)(ws + 6241808);                  // 1 (hidtr counter)
  int*   gdone = (int*)(ws + 6241809);                  // 1 (gather counter)
  int*   offs  = (int*)(ws + 6241824);                  // 10,001 (pad to 6251832)
  int*   cursor= (int*)(ws + 6251832);                  // 10,000
  unsigned short* G  = (unsigned short*)(ws + 6271832); // 102,400 shorts (16B-aligned)
  unsigned short* hb = (unsigned short*)(ws + 6323032); // 6,400,000 shorts
  // end = 9,523,032 floats ≈ 38.1 MB

  hipMemsetAsync(cntn, 0, (size_t)10002 * 4, stream);   // cntn + done + gdone
  k_hidtr<<<HBLK + TBLK, 256, 0, stream>>>(edge_attr, fc1w, fc1b, fc2w, eidx,
                                           cntn, done, offs, cursor, hb, G);
  k_tp<<<782, 256, 0, stream>>>(hb, G, fc2b, eidx, node_attr, edge_sh, cursor, tp);
  k_gather<<<640, 256, 0, stream>>>(tp, offs, node_attr, pre, pstat, gdone, stats);
  k_norm<<<(NNODES * DNODE + 255) / 256, 256, 0, stream>>>(pre, stats, gs, bs, gv, (float*)d_out);
}

// Round 8
// 195.921 us; speedup vs baseline: 1.6786x; 1.6786x over previous
//
#include <hip/hip_runtime.h>
#include <stdint.h>

#define NNODES 10000
#define NEDGES 100000
#define DNODE 56
#define JTOT 1600
#define EBLK 782    // k_hid MFMA blocks (128 edges each)
#define TBLK 400    // G-transpose blocks

typedef __attribute__((ext_vector_type(8))) short short8;
typedef __attribute__((ext_vector_type(4))) float floatx4;

__device__ __forceinline__ unsigned short f2bf(float f) {
  unsigned u = __float_as_uint(f);
  u = u + 0x7fffu + ((u >> 16) & 1u);
  return (unsigned short)(u >> 16);
}
__device__ __forceinline__ float bf2f(unsigned short u) {
  return __uint_as_float(((unsigned)u) << 16);
}

__device__ __forceinline__ float mishf(float x) {
  float e = __expf(x);
  float z = 1.f + e; z = z * z;
  float t = (z - 1.f) / (z + 1.f);
  t = (x > 40.f) ? 1.f : t;
  return x * t;
}

// async 16B global -> LDS; lds base must be wave-uniform (HW adds lane*16)
__device__ __forceinline__ void async_ld16(void* lds, const void* gp) {
  __builtin_amdgcn_global_load_lds(
      (const __attribute__((address_space(1))) unsigned int*)gp,
      (__attribute__((address_space(3))) unsigned int*)lds, 16, 0, 0);
}

// ---- fused: blocks [0,EBLK) h = mish(ea@fc1+b1) via MFMA + src histogram;
//             [EBLK,EBLK+TBLK) G = bf16(fc2w^T) pre-swizzled for k_tp LDS frags.
__global__ __launch_bounds__(256, 4) void k_hidtr(const float* __restrict__ ea,
                                                  const float* __restrict__ fc1w,
                                                  const float* __restrict__ fc1b,
                                                  const float* __restrict__ fc2w,
                                                  const int* __restrict__ eidx,
                                                  int* __restrict__ cntn,
                                                  unsigned short* __restrict__ hb,
                                                  unsigned short* __restrict__ G) {
  const int bid = blockIdx.x, tid = threadIdx.x;
  if (bid >= EBLK) {          // ---- G transpose+cast (pre-swizzled)
    int idx = (bid - EBLK) * 256 + tid;
    if (idx < 64 * JTOT) {
      int jt = idx >> 10, r = idx & 1023;
      int c = r >> 6, w = r & 63;
      int slot = w >> 3, s = w & 7;
      int g = slot ^ (c & 7);
      int k = g * 8 + s;
      int j = jt * 16 + c;
      G[idx] = f2bf(fc2w[k * JTOT + j]);
    }
    return;
  }
  // ---- hidden GEMM: 128 edges/block, 4 waves x 32 edges, MFMA 16x16x32 bf16
  __shared__ unsigned short T[64 * 72];    // fc1^T bf16, +8 pad (9,216 B)
  __shared__ unsigned short E[128 * 72];   // ea bf16 -> h staging (18,432 B)
  __shared__ float b1s[64];
  const int e0 = bid * 128;
  if (tid < 128) {
    int e = e0 + tid;
    if (e < NEDGES) atomicAdd(&cntn[eidx[e]], 1);
  }
  if (tid < 64) b1s[tid] = fc1b[tid];
  // stage T[j][k] = bf16(fc1w[k][j]): 1024 float4s, 4/thread
  #pragma unroll
  for (int it = 0; it < 4; it++) {
    int q = tid + 256 * it;
    int k = q >> 4, j4 = (q & 15) * 4;
    float4 v = *(const float4*)(fc1w + (size_t)q * 4);
    T[(j4+0)*72 + k] = f2bf(v.x);
    T[(j4+1)*72 + k] = f2bf(v.y);
    T[(j4+2)*72 + k] = f2bf(v.z);
    T[(j4+3)*72 + k] = f2bf(v.w);
  }
  // stage E[e][k] = bf16(ea[e0+e][k]): 2048 float4s coalesced, 8/thread
  #pragma unroll
  for (int it = 0; it < 8; it++) {
    int q = tid + 256 * it;
    int e = q >> 4, k4 = (q & 15) * 4;
    int ge = e0 + e;
    float4 v = (ge < NEDGES) ? *(const float4*)(ea + (size_t)ge * 64 + k4)
                             : make_float4(0.f, 0.f, 0.f, 0.f);
    ushort4 p;
    p.x = f2bf(v.x); p.y = f2bf(v.y); p.z = f2bf(v.z); p.w = f2bf(v.w);
    *(ushort4*)(&E[e*72 + k4]) = p;
  }
  __syncthreads();

  const int wave = tid >> 6, lane = tid & 63, col = lane & 15, rg = lane >> 4;
  short8 bf[2][2];
  #pragma unroll
  for (int nt = 0; nt < 2; nt++) {
    int er = wave*32 + nt*16 + col;
    bf[nt][0] = *(const short8*)(&E[er*72 + rg*8]);
    bf[nt][1] = *(const short8*)(&E[er*72 + 32 + rg*8]);
  }
  floatx4 acc[4][2];
  #pragma unroll
  for (int jt = 0; jt < 4; jt++) {
    int j = jt*16 + col;
    short8 a0 = *(const short8*)(&T[j*72 + rg*8]);
    short8 a1 = *(const short8*)(&T[j*72 + 32 + rg*8]);
    float4 bb = *(const float4*)(&b1s[jt*16 + rg*4]);
    #pragma unroll
    for (int nt = 0; nt < 2; nt++) {
      floatx4 c = {bb.x, bb.y, bb.z, bb.w};
      c = __builtin_amdgcn_mfma_f32_16x16x32_bf16(a0, bf[nt][0], c, 0, 0, 0);
      c = __builtin_amdgcn_mfma_f32_16x16x32_bf16(a1, bf[nt][1], c, 0, 0, 0);
      acc[jt][nt] = c;
    }
  }
  // mish -> bf16 -> E (own-wave rows; same-wave DS is in-order, no barrier)
  #pragma unroll
  for (int jt = 0; jt < 4; jt++)
    #pragma unroll
    for (int nt = 0; nt < 2; nt++) {
      ushort4 p;
      p.x = f2bf(mishf(acc[jt][nt][0]));
      p.y = f2bf(mishf(acc[jt][nt][1]));
      p.z = f2bf(mishf(acc[jt][nt][2]));
      p.w = f2bf(mishf(acc[jt][nt][3]));
      *(ushort4*)(&E[(wave*32 + nt*16 + col)*72 + jt*16 + rg*4]) = p;
    }
  // coalesced writeout: wave's 32 rows x 8 granules(16B)
  #pragma unroll
  for (int it = 0; it < 4; it++) {
    int g = it*64 + lane;
    int r = g >> 3, c = g & 7;
    int ge = e0 + wave*32 + r;
    if (ge < NEDGES) {
      short8 v = *(const short8*)(&E[(wave*32 + r)*72 + c*8]);
      *(short8*)(hb + (size_t)ge*64 + c*8) = v;
    }
  }
}

// ---- scan: offs/cursor from cntn (single block, R4-proven)
__global__ __launch_bounds__(1024) void k_scan(const int* __restrict__ cntn,
                                               int* __restrict__ offs,
                                               int* __restrict__ cursor) {
  __shared__ int ts[1024];
  int t = threadIdx.x;
  int base = t * 10;
  int loc[10]; int s = 0;
  #pragma unroll
  for (int i = 0; i < 10; i++) {
    int idx = base + i;
    int v = (idx < NNODES) ? cntn[idx] : 0;
    loc[i] = s; s += v;
  }
  ts[t] = s;
  __syncthreads();
  for (int off = 1; off < 1024; off <<= 1) {
    int v = (t >= off) ? ts[t - off] : 0;
    __syncthreads();
    ts[t] += v;
    __syncthreads();
  }
  int excl = (t == 0) ? 0 : ts[t - 1];
  #pragma unroll
  for (int i = 0; i < 10; i++) {
    int idx = base + i;
    if (idx < NNODES) { int o = excl + loc[i]; offs[idx] = o; cursor[idx] = o; }
  }
  if (t == 1023) offs[NNODES] = ts[1023];
}

// ---- fused GEMM2 + tensor product. 256 thr = 4 waves x 32 edges.
// G double-buffered 4-tile chunks (8KB) via global_load_lds, blockIdx%25 stagger.
// LDS ~39.7KB -> 4 blocks/CU; launch_bounds(256,4) cap 128 VGPR (measured 88).
__global__ __launch_bounds__(256, 4) void k_tp(
    const unsigned short* __restrict__ hb,
    const unsigned short* __restrict__ G,     // pre-swizzled
    const float* __restrict__ fc2b,
    const int* __restrict__ eidx,
    const float* __restrict__ node_attr,
    const float* __restrict__ edge_sh,
    int* __restrict__ cursor,
    float* __restrict__ tp) {
  __shared__ short Gs[2][4 * 1024];           // 16,384 B
  __shared__ unsigned short wls[4][64 * 32];  // 16,384 B bf16 coef tables
  __shared__ float b2s[JTOT];                 //  6,400 B
  __shared__ int pos_s[4][32];                //    512 B
  const int tid = threadIdx.x;
  const int wave = tid >> 6, lane = tid & 63;
  for (int i = tid; i < JTOT; i += 256) b2s[i] = fc2b[i];

  const int e0w = blockIdx.x * 128 + wave * 32;
  unsigned short* Wt = &wls[wave][0];
  {
    int el = lane & 31, hh = lane >> 5;
    int e = e0w + el;
    bool valid = e < NEDGES;
    int dst = valid ? eidx[NEDGES + e] : 0;
    const float* na = node_attr + (size_t)dst * DNODE;
    if (hh == 0) {
      pos_s[wave][el] = valid ? atomicAdd(&cursor[eidx[e]], 1) : 0;
      #pragma unroll
      for (int u = 0; u < 32; u += 4) {
        float4 v = valid ? *(const float4*)(na + u) : make_float4(0.f,0.f,0.f,0.f);
        Wt[(u+0)*32 + el] = f2bf(v.x);
        Wt[(u+1)*32 + el] = f2bf(v.y);
        Wt[(u+2)*32 + el] = f2bf(v.z);
        Wt[(u+3)*32 + el] = f2bf(v.w);
      }
    } else {
      float4 sh = valid ? *(const float4*)(edge_sh + 4*(size_t)e) : make_float4(0.f,0.f,0.f,0.f);
      const float rs3 = 0.57735026918962576f;
      #pragma unroll
      for (int u = 0; u < 8; u++) {
        float v0 = valid ? na[32 + u*3 + 0] : 0.f;
        float v1 = valid ? na[32 + u*3 + 1] : 0.f;
        float v2 = valid ? na[32 + u*3 + 2] : 0.f;
        Wt[(32 + u*3 + 0)*32 + el] = f2bf(v0);
        Wt[(32 + u*3 + 1)*32 + el] = f2bf(v1);
        Wt[(32 + u*3 + 2)*32 + el] = f2bf(v2);
        Wt[(56 + u)*32 + el] = f2bf((v0*sh.y + v1*sh.z + v2*sh.w) * rs3);
      }
    }
  }

  const int col = lane & 15, rg = lane >> 4, rgh = rg >> 1;
  const int g0 = (rg ^ (col & 7)) * 8;
  const int g1 = ((rg + 4) ^ (col & 7)) * 8;
  float sh0c[2], sh1c[2][3];
  bool vld[2];
  short8 bfrag[2][2];
  const short8 zfrag = {0,0,0,0,0,0,0,0};
  #pragma unroll
  for (int nt = 0; nt < 2; nt++) {
    int e = e0w + nt*16 + col;
    bool v = e < NEDGES; vld[nt] = v;
    if (v) {
      float4 sh = *(const float4*)(edge_sh + 4*(size_t)e);
      sh0c[nt] = sh.x; sh1c[nt][0] = sh.y; sh1c[nt][1] = sh.z; sh1c[nt][2] = sh.w;
      const unsigned short* hp = hb + (size_t)e * 64;
      bfrag[nt][0] = *(const short8*)(hp + rg*8);
      bfrag[nt][1] = *(const short8*)(hp + 32 + rg*8);
    } else {
      sh0c[nt] = 0.f; sh1c[nt][0] = sh1c[nt][1] = sh1c[nt][2] = 0.f;
      bfrag[nt][0] = zfrag; bfrag[nt][1] = zfrag;
    }
  }

  float sacc[2][8], vacc[2][12];
  #pragma unroll
  for (int nt = 0; nt < 2; nt++) {
    #pragma unroll
    for (int i = 0; i < 8; i++) sacc[nt][i] = 0.f;
    #pragma unroll
    for (int i = 0; i < 12; i++) vacc[nt][i] = 0.f;
  }

  // stage chunk ch (4 tiles = 4096 shorts = 512 granules) into Gs[b]
  auto stage = [&](int ch, int b) {
    const unsigned short* gsrc = G + (size_t)ch * 4096 + tid * 8;
    #pragma unroll
    for (int i = 0; i < 2; i++)
      async_ld16(&Gs[b][(i*256 + wave*64) * 8], gsrc + i*256*8);
  };

  const int cc0 = blockIdx.x % 25;
  stage(cc0, 0);
  __syncthreads();

  int buf = 0;
  #pragma unroll 1
  for (int cc = 0; cc < 25; cc++) {
    int c = cc0 + cc; if (c >= 25) c -= 25;
    if (cc < 24) { int cn = c + 1; if (cn >= 25) cn = 0; stage(cn, buf ^ 1); }
    #pragma unroll
    for (int t = 0; t < 4; t++) {
      const int jt = c * 4 + t;
      const short* gb = &Gs[buf][t * 1024];
      short8 x0 = *(const short8*)(gb + col*64 + g0);
      short8 x1 = *(const short8*)(gb + col*64 + g1);
      float4 bb = *(const float4*)&b2s[jt*16 + rg*4];
      floatx4 acc[2];
      #pragma unroll
      for (int nt = 0; nt < 2; nt++) {
        floatx4 a = {bb.x, bb.y, bb.z, bb.w};
        a = __builtin_amdgcn_mfma_f32_16x16x32_bf16(x0, bfrag[nt][0], a, 0, 0, 0);
        a = __builtin_amdgcn_mfma_f32_16x16x32_bf16(x1, bfrag[nt][1], a, 0, 0, 0);
        acc[nt] = a;
      }
      if (jt < 64) {                   // w1
        const int u = jt >> 1, p = jt & 1;
        #pragma unroll
        for (int nt = 0; nt < 2; nt++) {
          float cf = bf2f(Wt[u*32 + nt*16 + col]) * sh0c[nt];
          #pragma unroll
          for (int r = 0; r < 4; r++)
            sacc[nt][p*4+r] = fmaf(cf, acc[nt][r], sacc[nt][p*4+r]);
        }
      } else if (jt < 68) {            // w2
        const int u = (jt - 64)*2 + rgh;
        #pragma unroll
        for (int nt = 0; nt < 2; nt++) {
          #pragma unroll
          for (int q = 0; q < 3; q++) {
            float cf = bf2f(Wt[(32 + u*3 + q)*32 + nt*16 + col]) * sh0c[nt];
            #pragma unroll
            for (int r = 0; r < 4; r++)
              vacc[nt][q*4+r] = fmaf(cf, acc[nt][r], vacc[nt][q*4+r]);
          }
        }
      } else if (jt < 84) {            // w3
        const int u = (jt - 68)*2 + rgh;
        #pragma unroll
        for (int nt = 0; nt < 2; nt++) {
          float sv = bf2f(Wt[u*32 + nt*16 + col]);
          #pragma unroll
          for (int q = 0; q < 3; q++) {
            float cf = sv * sh1c[nt][q];
            #pragma unroll
            for (int r = 0; r < 4; r++)
              vacc[nt][q*4+r] = fmaf(cf, acc[nt][r], vacc[nt][q*4+r]);
          }
        }
      } else {                         // w4
        const int u = (jt - 84) >> 1, p = jt & 1;
        #pragma unroll
        for (int nt = 0; nt < 2; nt++) {
          float cf = bf2f(Wt[(56 + u)*32 + nt*16 + col]);
          #pragma unroll
          for (int r = 0; r < 4; r++)
            sacc[nt][p*4+r] = fmaf(cf, acc[nt][r], sacc[nt][p*4+r]);
        }
      }
    }
    buf ^= 1;
    __syncthreads();
  }

  // ---- epilogue: direct stores
  const float ascale = 0.15811388300841897f;   // 1/sqrt(40)
  #pragma unroll
  for (int nt = 0; nt < 2; nt++) {
    int el = nt*16 + col;
    float* rowp = tp + (size_t)pos_s[wave][el] * DNODE;
    if (vld[nt]) {
      #pragma unroll
      for (int p = 0; p < 2; p++) {
        float4 v = make_float4(ascale*sacc[nt][p*4+0], ascale*sacc[nt][p*4+1],
                               ascale*sacc[nt][p*4+2], ascale*sacc[nt][p*4+3]);
        *(float4*)(rowp + p*16 + rg*4) = v;
      }
    }
    float vtot[12];
    #pragma unroll
    for (int k = 0; k < 12; k++)
      vtot[k] = (vacc[nt][k] + __shfl_xor(vacc[nt][k], 32)) * ascale;
    if (rg < 2 && vld[nt]) {
      float tmp[12];
      #pragma unroll
      for (int q = 0; q < 3; q++)
        #pragma unroll
        for (int r = 0; r < 4; r++) tmp[r*3 + q] = vtot[q*4 + r];
      #pragma unroll
      for (int j = 0; j < 3; j++)
        *(float4*)(rowp + 32 + (rg & 1)*12 + j*4) = *(float4*)&tmp[j*4];
    }
  }
}

// ---- per-node mean + residual + BN partials (contiguous CSR rows)
__global__ __launch_bounds__(256) void k_gather(const float* __restrict__ tp,
                                                const int* __restrict__ offs,
                                                const float* __restrict__ node_attr,
                                                float* __restrict__ pre,
                                                float* __restrict__ pstat) {
  __shared__ float redS[4*64], redQ[4*64];
  int t = threadIdx.x, wave = t >> 6, lane = t & 63;
  int gw = blockIdx.x * 4 + wave;
  const int W = 640 * 4;
  int off = (lane < DNODE) ? lane : 0;
  float ssum = 0.f, ssq = 0.f;
  for (int n = gw; n < NNODES; n += W) {
    int beg = offs[n], end = offs[n+1];
    float acc = 0.f;
    int i = beg;
    for (; i + 4 <= end; i += 4) {
      float v0 = tp[(size_t)(i+0)*DNODE + off];
      float v1 = tp[(size_t)(i+1)*DNODE + off];
      float v2 = tp[(size_t)(i+2)*DNODE + off];
      float v3 = tp[(size_t)(i+3)*DNODE + off];
      acc += (v0 + v1) + (v2 + v3);
    }
    for (; i < end; i++) acc += tp[(size_t)i*DNODE + off];
    int c = end - beg; if (c < 1) c = 1;
    float m = acc / (float)c + node_attr[(size_t)n*DNODE + off];
    if (lane < DNODE) { pre[(size_t)n*DNODE + lane] = m; ssum += m; ssq += m*m; }
  }
  redS[wave*64 + lane] = ssum;
  redQ[wave*64 + lane] = ssq;
  __syncthreads();
  if (wave == 0 && lane < DNODE) {
    float a = redS[lane] + redS[64+lane] + redS[128+lane] + redS[192+lane];
    float b = redQ[lane] + redQ[64+lane] + redQ[128+lane] + redQ[192+lane];
    pstat[(size_t)blockIdx.x*112 + lane] = a;
    pstat[(size_t)blockIdx.x*112 + 56 + lane] = b;
  }
}

__global__ __launch_bounds__(256) void k_stats(const float* __restrict__ pstat,
                                               float* __restrict__ stats) {
  int f = blockIdx.x * 4 + (threadIdx.x >> 6);
  int lane = threadIdx.x & 63;
  float v = 0.f;
  for (int b = lane; b < 640; b += 64) v += pstat[(size_t)b*112 + f];
  #pragma unroll
  for (int o = 32; o; o >>= 1) v += __shfl_xor(v, o);
  if (lane == 0) stats[f] = v;
}

__global__ __launch_bounds__(256) void k_norm(const float* __restrict__ pre,
                                              const float* __restrict__ stats,
                                              const float* __restrict__ gs,
                                              const float* __restrict__ bs,
                                              const float* __restrict__ gv,
                                              float* __restrict__ out) {
  int idx = blockIdx.x * 256 + threadIdx.x;
  if (idx >= NNODES * DNODE) return;
  int n = idx / DNODE;
  int d = idx - n * DNODE;
  float val = pre[idx];
  const float invN = 1.f / (float)NNODES;
  float res;
  if (d < 32) {
    float mu = stats[d] * invN;
    float var = stats[56 + d] * invN - mu * mu;
    res = (val - mu) * rsqrtf(var + 1e-4f) * gs[d] + bs[d];
  } else {
    int wi = (d - 32) / 3;
    float vn = (stats[56 + 32 + wi*3] + stats[56 + 32 + wi*3 + 1] +
                stats[56 + 32 + wi*3 + 2]) * (invN / 3.f);
    res = val * rsqrtf(vn + 1e-4f) * gv[wi];
  }
  out[idx] = res;
}

extern "C" void kernel_launch(void* const* d_in, const int* in_sizes, int n_in,
                              void* d_out, int out_size, void* d_ws, size_t ws_size,
                              hipStream_t stream) {
  const float* node_attr = (const float*)d_in[0];
  const int*   eidx      = (const int*)d_in[1];
  const float* edge_attr = (const float*)d_in[2];
  const float* edge_sh   = (const float*)d_in[3];
  const float* fc1w      = (const float*)d_in[4];
  const float* fc1b      = (const float*)d_in[5];
  const float* fc2w      = (const float*)d_in[6];
  const float* fc2b      = (const float*)d_in[7];
  const float* gs        = (const float*)d_in[8];
  const float* bs        = (const float*)d_in[9];
  const float* gv        = (const float*)d_in[10];

  float* ws = (float*)d_ws;
  float* tp    = ws;                                    // 5,600,000
  float* pre   = ws + 5600000;                          // 560,000
  float* stats = ws + 6160000;                          // 112 (pad 128)
  float* pstat = ws + 6160128;                          // 640*112 = 71,680
  int*   cntn  = (int*)(ws + 6231808);                  // 10,000
  int*   offs  = (int*)(ws + 6241808);                  // 10,001 (pad 10,008)
  int*   cursor= (int*)(ws + 6251816);                  // 10,000
  unsigned short* G  = (unsigned short*)(ws + 6261816); // 102,400 shorts (16B-aligned)
  unsigned short* hb = (unsigned short*)(ws + 6313016); // 6,400,000 shorts

  hipMemsetAsync(cntn, 0, (size_t)10000 * 4, stream);
  k_hidtr<<<EBLK + TBLK, 256, 0, stream>>>(edge_attr, fc1w, fc1b, fc2w, eidx, cntn, hb, G);
  k_scan<<<1, 1024, 0, stream>>>(cntn, offs, cursor);
  k_tp<<<782, 256, 0, stream>>>(hb, G, fc2b, eidx, node_attr, edge_sh, cursor, tp);
  k_gather<<<640, 256, 0, stream>>>(tp, offs, node_attr, pre, pstat);
  k_stats<<<28, 256, 0, stream>>>(pstat, stats);
  k_norm<<<(NNODES * DNODE + 255) / 256, 256, 0, stream>>>(pre, stats, gs, bs, gv, (float*)d_out);
}